// Round 1
// baseline (160.231 us; speedup 1.0000x reference)
//
#include <hip/hip_runtime.h>
#include <math.h>

#define BB 4
#define CCH 128     // channels
#define HH 64
#define WW 256
#define RR 8
#define KWIN 17
#define TW 32       // output w-tile per block
#define TWH 48      // TW + 2R (halo)
#define NTHREADS 256
#define CCHUNK 8    // c-rows of W staged per chunk

__global__ __launch_bounds__(NTHREADS, 2)
void attn1d_fused(const float* __restrict__ feature,
                  const float* __restrict__ position,
                  const float* __restrict__ Wq, const float* __restrict__ bq,
                  const float* __restrict__ Wk, const float* __restrict__ bk,
                  float* __restrict__ out)
{
    __shared__ float f_lds[CCH][TWH + 1];   // 128 x 49  (v and GEMM input)
    __shared__ float k_lds[CCH][TWH + 1];   // 128 x 49
    __shared__ float q_lds[CCH][TW + 1];    // 128 x 33
    __shared__ float w_ch[CCHUNK][2 * CCH]; // 8 x 256   (Wq|Wk chunk, [c][o])
    __shared__ float s_lds[TW][KWIN + 1];   // 32 x 18

    const int t = threadIdx.x;
    int blk = blockIdx.x;
    const int wt = blk & 7;          // W/TW = 8
    const int bh = blk >> 3;         // b*H + h
    const int h  = bh & (HH - 1);
    const int b  = bh >> 6;
    const int w0 = wt * TW - RR;     // global w of local col 0

    const int base = ((b * CCH) * HH + h) * WW;   // offset of (b, c=0, h, w=0)

    // ---------------- Phase A: stage f = feature + position (zero-pad OOB) ----
    for (int idx = t; idx < CCH * TWH; idx += NTHREADS) {
        const int c  = idx / TWH;
        const int wl = idx - c * TWH;
        const int w  = w0 + wl;
        float v = 0.f;
        if (w >= 0 && w < WW) {
            const int off = base + c * (HH * WW) + w;
            v = feature[off] + position[off];
        }
        f_lds[c][wl] = v;
    }
    __syncthreads();

    // ---------------- Phase B: q = Wq f + bq, k = Wk f + bk -------------------
    // 256 outputs rows (o<128 -> q, o>=128 -> k) x 48 cols.
    // thread: og = t>>3 owns o in [og*8, og*8+8); wg = t&7 owns w in [wg*6, wg*6+6)
    const int og = t >> 3;
    const int wg = t & 7;
    const int o_base = og * 8;
    const int w_base = wg * 6;

    float acc[8][6];
    #pragma unroll
    for (int j = 0; j < 8; ++j)
        #pragma unroll
        for (int i = 0; i < 6; ++i) acc[j][i] = 0.f;

    for (int cc0 = 0; cc0 < CCH; cc0 += CCHUNK) {
        __syncthreads();   // protect w_ch reuse
        {
            // thread t stages W row o=t, columns cc0..cc0+7 (32B contiguous)
            const float* Wsrc = (t < CCH) ? (Wq + t * CCH + cc0)
                                          : (Wk + (t - CCH) * CCH + cc0);
            const float4 a0 = *(const float4*)(Wsrc);
            const float4 a1 = *(const float4*)(Wsrc + 4);
            w_ch[0][t] = a0.x; w_ch[1][t] = a0.y; w_ch[2][t] = a0.z; w_ch[3][t] = a0.w;
            w_ch[4][t] = a1.x; w_ch[5][t] = a1.y; w_ch[6][t] = a1.z; w_ch[7][t] = a1.w;
        }
        __syncthreads();

        #pragma unroll
        for (int cc = 0; cc < CCHUNK; ++cc) {
            const int c = cc0 + cc;
            float fv[6];
            #pragma unroll
            for (int i = 0; i < 6; ++i) fv[i] = f_lds[c][w_base + i];
            const float4 wv0 = *(const float4*)&w_ch[cc][o_base];
            const float4 wv1 = *(const float4*)&w_ch[cc][o_base + 4];
            const float wv[8] = {wv0.x, wv0.y, wv0.z, wv0.w,
                                 wv1.x, wv1.y, wv1.z, wv1.w};
            #pragma unroll
            for (int j = 0; j < 8; ++j)
                #pragma unroll
                for (int i = 0; i < 6; ++i)
                    acc[j][i] = fmaf(wv[j], fv[i], acc[j][i]);
        }
    }

    // write q (cols 8..39 -> q_lds[.][0..31]) and k (all 48 cols, zero OOB)
    if (o_base < CCH) {
        #pragma unroll
        for (int j = 0; j < 8; ++j) {
            const int o = o_base + j;
            const float bias = bq[o];
            #pragma unroll
            for (int i = 0; i < 6; ++i) {
                const int wl = w_base + i;
                if (wl >= RR && wl < RR + TW)
                    q_lds[o][wl - RR] = acc[j][i] + bias;
            }
        }
    } else {
        #pragma unroll
        for (int j = 0; j < 8; ++j) {
            const int ok = o_base + j - CCH;
            const float bias = bk[ok];
            #pragma unroll
            for (int i = 0; i < 6; ++i) {
                const int wl = w_base + i;
                const int w = w0 + wl;
                k_lds[ok][wl] = (w >= 0 && w < WW) ? (acc[j][i] + bias) : 0.f;
            }
        }
    }
    __syncthreads();

    // ---------------- Phase C: scores[w][j] = q[.,w] . k[.,w+j] / sqrt(C) -----
    {
        const int wS = t & 31;
        const int jg = t >> 5;    // 0..7; handles j = jg, jg+8, (jg==0 -> 16)
        float s1 = 0.f, s2 = 0.f, s3 = 0.f;
        #pragma unroll 8
        for (int c = 0; c < CCH; ++c) {
            const float qv = q_lds[c][wS];
            s1 = fmaf(qv, k_lds[c][wS + jg],     s1);
            s2 = fmaf(qv, k_lds[c][wS + jg + 8], s2);
            s3 = fmaf(qv, k_lds[c][wS + 16],     s3);
        }
        const float inv_scale = 0.08838834764831845f;  // 1/sqrt(128)
        s_lds[wS][jg]     = s1 * inv_scale;
        s_lds[wS][jg + 8] = s2 * inv_scale;
        if (jg == 0) s_lds[wS][16] = s3 * inv_scale;
    }
    __syncthreads();

    // ---------------- softmax over the 17 taps (incl. exact zeros at pads) ---
    if (t < TW) {
        float mx = -3.0e38f;
        #pragma unroll
        for (int j = 0; j < KWIN; ++j) mx = fmaxf(mx, s_lds[t][j]);
        float e[KWIN];
        float sum = 0.f;
        #pragma unroll
        for (int j = 0; j < KWIN; ++j) { e[j] = expf(s_lds[t][j] - mx); sum += e[j]; }
        const float inv = 1.f / sum;
        #pragma unroll
        for (int j = 0; j < KWIN; ++j) s_lds[t][j] = e[j] * inv;
    }
    __syncthreads();

    // ---------------- Phase D: out[c][w] = sum_j attn[w][j] * f[c][w+j] ------
    {
        const int wD = t & 31;
        const int cg = t >> 5;        // 0..7
        const int cb = cg * 16;
        float o_acc[16];
        #pragma unroll
        for (int i = 0; i < 16; ++i) o_acc[i] = 0.f;
        #pragma unroll
        for (int j = 0; j < KWIN; ++j) {
            const float av = s_lds[wD][j];
            #pragma unroll
            for (int i = 0; i < 16; ++i)
                o_acc[i] = fmaf(av, f_lds[cb + i][wD + j], o_acc[i]);
        }
        const int wgl = wt * TW + wD;
        #pragma unroll
        for (int i = 0; i < 16; ++i)
            out[base + (cb + i) * (HH * WW) + wgl] = o_acc[i];
    }
}

extern "C" void kernel_launch(void* const* d_in, const int* in_sizes, int n_in,
                              void* d_out, int out_size, void* d_ws, size_t ws_size,
                              hipStream_t stream) {
    const float* feature  = (const float*)d_in[0];
    const float* position = (const float*)d_in[1];
    const float* Wq = (const float*)d_in[2];
    const float* bq = (const float*)d_in[3];
    const float* Wk = (const float*)d_in[4];
    const float* bk = (const float*)d_in[5];
    float* out = (float*)d_out;

    const dim3 grid(BB * HH * (WW / TW));   // 2048 blocks
    attn1d_fused<<<grid, NTHREADS, 0, stream>>>(feature, position, Wq, bq, Wk, bk, out);
}

// Round 2
// 100.847 us; speedup vs baseline: 1.5888x; 1.5888x over previous
//
#include <hip/hip_runtime.h>
#include <hip/hip_bf16.h>
#include <math.h>

#define BB 4
#define CCH 128     // channels
#define HH 64
#define WW 256
#define RR 8
#define KWIN 17
#define TW 32       // output w-tile per block
#define TWH 48      // TW + 2R (halo)
#define NTHREADS 256
#define FBT_LD 136  // 128 + 8 pad: keeps 16B alignment, 2-way banks (free)

typedef __attribute__((ext_vector_type(8))) short short8;
typedef __attribute__((ext_vector_type(4))) float f32x4;

__device__ __forceinline__ short f2bf(float x) {
    union { __hip_bfloat16 b; short s; } u;
    u.b = __float2bfloat16(x);
    return u.s;
}

__global__ __launch_bounds__(NTHREADS, 2)
void attn1d_fused(const float* __restrict__ feature,
                  const float* __restrict__ position,
                  const float* __restrict__ Wq, const float* __restrict__ bq,
                  const float* __restrict__ Wk, const float* __restrict__ bk,
                  float* __restrict__ out)
{
    __shared__ float f_lds[CCH][TWH + 1];   // 25088 B  (v, fp32)
    __shared__ float k_lds[CCH][TWH + 1];   // 25088 B
    __shared__ float q_lds[CCH][TW];        // 16384 B
    __shared__ float s_lds[TW][KWIN];       //  2176 B
    __shared__ short fBt[TWH][FBT_LD];      // 13056 B  (f^T bf16, GEMM B-operand)
                                            // total 81792 B -> 2 blocks/CU

    const int t    = threadIdx.x;
    const int wid  = t >> 6;     // wave 0..3
    const int lane = t & 63;
    const int lrow = lane & 15;  // m/n index within fragment
    const int lgrp = lane >> 4;  // k-group / row-group

    const int blk = blockIdx.x;
    const int wt = blk & 7;          // W/TW = 8
    const int bh = blk >> 3;
    const int h  = bh & (HH - 1);
    const int b  = bh >> 6;
    const int w0 = wt * TW - RR;
    const int base = ((b * CCH) * HH + h) * WW;

    // ---- A-fragments: rows of Wq (waves 0,1) / Wk (waves 2,3), bf16 in regs --
    const int   mrow = (wid & 1) * 64;              // row base within the matrix
    const float* Wmat = (wid < 2) ? Wq : Wk;
    const float* bvec = (wid < 2) ? bq : bk;

    short8 afrag[4][4];   // [mf][kk]
    #pragma unroll
    for (int mf = 0; mf < 4; ++mf) {
        const float* wrow = Wmat + (mrow + mf * 16 + lrow) * CCH;
        #pragma unroll
        for (int kk = 0; kk < 4; ++kk) {
            const float* p = wrow + kk * 32 + lgrp * 8;
            const float4 a0 = *(const float4*)p;
            const float4 a1 = *(const float4*)(p + 4);
            short8 s;
            s[0] = f2bf(a0.x); s[1] = f2bf(a0.y); s[2] = f2bf(a0.z); s[3] = f2bf(a0.w);
            s[4] = f2bf(a1.x); s[5] = f2bf(a1.y); s[6] = f2bf(a1.z); s[7] = f2bf(a1.w);
            afrag[mf][kk] = s;
        }
    }
    float bias_r[4][4];   // bias for C/D rows: mf*16 + lgrp*4 + reg
    #pragma unroll
    for (int mf = 0; mf < 4; ++mf)
        #pragma unroll
        for (int reg = 0; reg < 4; ++reg)
            bias_r[mf][reg] = bvec[mrow + mf * 16 + lgrp * 4 + reg];

    // ---------------- Phase A: stage f (fp32) + f^T (bf16), zero-pad OOB -----
    for (int idx = t; idx < CCH * TWH; idx += NTHREADS) {
        const int c  = idx / TWH;
        const int wl = idx - c * TWH;
        const int w  = w0 + wl;
        float v = 0.f;
        if (w >= 0 && w < WW) {
            const int off = base + c * (HH * WW) + w;
            v = feature[off] + position[off];
        }
        f_lds[c][wl] = v;
        fBt[wl][c]   = f2bf(v);
    }
    __syncthreads();

    // ---------------- Phase B: q,k = [Wq;Wk] f + bias via MFMA ----------------
    f32x4 acc[4][3];   // [mf][nf]: wave tile 64(o) x 48(w)
    #pragma unroll
    for (int mf = 0; mf < 4; ++mf)
        #pragma unroll
        for (int nf = 0; nf < 3; ++nf)
            acc[mf][nf] = (f32x4){0.f, 0.f, 0.f, 0.f};

    #pragma unroll
    for (int kk = 0; kk < 4; ++kk) {
        short8 bfr[3];
        #pragma unroll
        for (int nf = 0; nf < 3; ++nf)
            bfr[nf] = *(const short8*)&fBt[nf * 16 + lrow][kk * 32 + lgrp * 8];
        #pragma unroll
        for (int mf = 0; mf < 4; ++mf)
            #pragma unroll
            for (int nf = 0; nf < 3; ++nf)
                acc[mf][nf] = __builtin_amdgcn_mfma_f32_16x16x32_bf16(
                    afrag[mf][kk], bfr[nf], acc[mf][nf], 0, 0, 0);
    }

    // write back: q -> q_lds (cols 8..39), k -> k_lds (all 48, zero OOB)
    if (wid < 2) {
        #pragma unroll
        for (int mf = 0; mf < 4; ++mf)
            #pragma unroll
            for (int nf = 0; nf < 3; ++nf) {
                const int wl = nf * 16 + lrow;
                if (wl >= RR && wl < RR + TW) {
                    #pragma unroll
                    for (int reg = 0; reg < 4; ++reg) {
                        const int o = mrow + mf * 16 + lgrp * 4 + reg;
                        q_lds[o][wl - RR] = acc[mf][nf][reg] + bias_r[mf][reg];
                    }
                }
            }
    } else {
        #pragma unroll
        for (int mf = 0; mf < 4; ++mf)
            #pragma unroll
            for (int nf = 0; nf < 3; ++nf) {
                const int wl = nf * 16 + lrow;
                const int w  = w0 + wl;
                const bool inb = (w >= 0 && w < WW);
                #pragma unroll
                for (int reg = 0; reg < 4; ++reg) {
                    const int o = mrow + mf * 16 + lgrp * 4 + reg;
                    k_lds[o][wl] = inb ? (acc[mf][nf][reg] + bias_r[mf][reg]) : 0.f;
                }
            }
    }
    __syncthreads();

    // ---------------- Phase C: scores[w][j] = q[.,w] . k[.,w+j] / sqrt(C) -----
    {
        const int wS = t & 31;
        const int jg = t >> 5;    // 0..7; handles j = jg, jg+8, (jg==0 -> 16)
        float s1 = 0.f, s2 = 0.f, s3 = 0.f;
        #pragma unroll 8
        for (int c = 0; c < CCH; ++c) {
            const float qv = q_lds[c][wS];
            s1 = fmaf(qv, k_lds[c][wS + jg],     s1);
            s2 = fmaf(qv, k_lds[c][wS + jg + 8], s2);
            s3 = fmaf(qv, k_lds[c][wS + 16],     s3);
        }
        const float inv_scale = 0.08838834764831845f;  // 1/sqrt(128)
        s_lds[wS][jg]     = s1 * inv_scale;
        s_lds[wS][jg + 8] = s2 * inv_scale;
        if (jg == 0) s_lds[wS][16] = s3 * inv_scale;
    }
    __syncthreads();

    // ---------------- softmax over the 17 taps (incl. exact zeros at pads) ---
    if (t < TW) {
        float mx = -3.0e38f;
        #pragma unroll
        for (int j = 0; j < KWIN; ++j) mx = fmaxf(mx, s_lds[t][j]);
        float e[KWIN];
        float sum = 0.f;
        #pragma unroll
        for (int j = 0; j < KWIN; ++j) { e[j] = __expf(s_lds[t][j] - mx); sum += e[j]; }
        const float inv = 1.f / sum;
        #pragma unroll
        for (int j = 0; j < KWIN; ++j) s_lds[t][j] = e[j] * inv;
    }
    __syncthreads();

    // ---------------- Phase D: out[c][w] = sum_j attn[w][j] * f[c][w+j] ------
    {
        const int wD = t & 31;
        const int cg = t >> 5;        // 0..7
        const int cb = cg * 16;
        float o_acc[16];
        #pragma unroll
        for (int i = 0; i < 16; ++i) o_acc[i] = 0.f;
        #pragma unroll
        for (int j = 0; j < KWIN; ++j) {
            const float av = s_lds[wD][j];
            #pragma unroll
            for (int i = 0; i < 16; ++i)
                o_acc[i] = fmaf(av, f_lds[cb + i][wD + j], o_acc[i]);
        }
        const int wgl = wt * TW + wD;
        #pragma unroll
        for (int i = 0; i < 16; ++i)
            out[base + (cb + i) * (HH * WW) + wgl] = o_acc[i];
    }
}

extern "C" void kernel_launch(void* const* d_in, const int* in_sizes, int n_in,
                              void* d_out, int out_size, void* d_ws, size_t ws_size,
                              hipStream_t stream) {
    const float* feature  = (const float*)d_in[0];
    const float* position = (const float*)d_in[1];
    const float* Wq = (const float*)d_in[2];
    const float* bq = (const float*)d_in[3];
    const float* Wk = (const float*)d_in[4];
    const float* bk = (const float*)d_in[5];
    float* out = (float*)d_out;

    const dim3 grid(BB * HH * (WW / TW));   // 2048 blocks
    attn1d_fused<<<grid, NTHREADS, 0, stream>>>(feature, position, Wq, bq, Wk, bk, out);
}

// Round 3
// 62.300 us; speedup vs baseline: 2.5719x; 1.6187x over previous
//
#include <hip/hip_runtime.h>
#include <hip/hip_bf16.h>
#include <math.h>

#define BB 4
#define CCH 128     // channels
#define HH 64
#define WW 256
#define RR 8
#define KWIN 17
#define TW 32       // output w-tile per block
#define TWH 48      // TW + 2R (halo)
#define NTHREADS 256
#define PIT 136     // pitch (shorts) for [row][c] bf16 arrays: 68 dw = 4 mod 32 -> clean b128
#define FAP 72      // fA pitch (shorts): 36 dw = 4 mod 32
#define STP 36      // St pitch (floats): 36 = 4 mod 32; band read bank = 5w mod 32 (distinct)
#define PTP 72      // Pt pitch (shorts)

typedef __attribute__((ext_vector_type(8))) short short8;
typedef __attribute__((ext_vector_type(4))) short short4v;
typedef __attribute__((ext_vector_type(4))) float f32x4;

__device__ __forceinline__ short f2bf(float x) {
    union { __hip_bfloat16 b; short s; } u;
    u.b = __float2bfloat16(x);
    return u.s;
}

__global__ __launch_bounds__(NTHREADS, 2)
void attn1d_fused(const float* __restrict__ feature,
                  const float* __restrict__ position,
                  const float* __restrict__ Wq, const float* __restrict__ bq,
                  const float* __restrict__ Wk, const float* __restrict__ bk,
                  float* __restrict__ out)
{
    // all bf16 operand arrays are fragment-layout friendly:
    //   [row][c] arrays (fBt,qT,kT): short8 B/A-frag reads at [row][kk*32+lgrp*8]
    __shared__ __align__(16) short fBt[TWH][PIT];  // f^T  [wl][c]   13056 B
    __shared__ __align__(16) short kT [TWH][PIT];  // k^T  [wl][c]   13056 B
    __shared__ __align__(16) short qT [TW ][PIT];  // q^T  [w][c]     8704 B
    __shared__ __align__(16) short fA [CCH][FAP];  // f    [c][wl]   18432 B (cols 48..63 zero)
    __shared__ __align__(16) float St [TWH][STP];  // S^T  [wl'][w]   6912 B
    __shared__ __align__(16) short Pt [TW ][PTP];  // P    [w][wl]    4608 B (zero-padded)
                                                   // total ~64.8 KB -> 2 blocks/CU

    const int t    = threadIdx.x;
    const int wid  = t >> 6;     // wave 0..3
    const int lane = t & 63;
    const int lrow = lane & 15;
    const int lgrp = lane >> 4;

    const int blk = blockIdx.x;
    const int wt = blk & 7;          // W/TW = 8
    const int bh = blk >> 3;
    const int h  = bh & (HH - 1);
    const int b  = bh >> 6;
    const int w0 = wt * TW - RR;
    const int base = ((b * CCH) * HH + h) * WW;

    // ---------------- zero fills (no data deps) ------------------------------
    {
        const short8 z = {0,0,0,0,0,0,0,0};
        short* p = &Pt[0][0];
        #pragma unroll
        for (int i = t; i < (TW * PTP) / 8; i += NTHREADS)   // 288 chunks
            *(short8*)(p + i * 8) = z;
        const int zc = t >> 1, zs = t & 1;                   // fA k-pad cols 48..63
        *(short8*)&fA[zc][48 + zs * 8] = z;
    }

    // ---- A-fragments: rows of Wq (waves 0,1) / Wk (waves 2,3), bf16 in regs --
    const int   mrow = (wid & 1) * 64;
    const float* Wmat = (wid < 2) ? Wq : Wk;
    const float* bvec = (wid < 2) ? bq : bk;

    short8 afrag[4][4];   // [mf][kk]
    #pragma unroll
    for (int mf = 0; mf < 4; ++mf) {
        const float* wrow = Wmat + (mrow + mf * 16 + lrow) * CCH;
        #pragma unroll
        for (int kk = 0; kk < 4; ++kk) {
            const float* p = wrow + kk * 32 + lgrp * 8;
            const float4 a0 = *(const float4*)p;
            const float4 a1 = *(const float4*)(p + 4);
            short8 s;
            s[0] = f2bf(a0.x); s[1] = f2bf(a0.y); s[2] = f2bf(a0.z); s[3] = f2bf(a0.w);
            s[4] = f2bf(a1.x); s[5] = f2bf(a1.y); s[6] = f2bf(a1.z); s[7] = f2bf(a1.w);
            afrag[mf][kk] = s;
        }
    }
    float bias_r[4][4];
    #pragma unroll
    for (int mf = 0; mf < 4; ++mf)
        #pragma unroll
        for (int reg = 0; reg < 4; ++reg)
            bias_r[mf][reg] = bvec[mrow + mf * 16 + lgrp * 4 + reg];

    // ---------------- Phase A: stage f as fBt (transposed) + fA --------------
    for (int idx = t; idx < CCH * (TWH / 4); idx += NTHREADS) {   // 1536 quads
        const int c  = idx / 12;
        const int wq = idx - c * 12;
        const int w  = w0 + wq * 4;          // quad fully in or out (w0 % 4 == 0)
        float4 fv = {0.f, 0.f, 0.f, 0.f};
        if (w >= 0 && w < WW) {
            const int off = base + c * (HH * WW) + w;
            const float4 fa = *(const float4*)(feature + off);
            const float4 pa = *(const float4*)(position + off);
            fv.x = fa.x + pa.x; fv.y = fa.y + pa.y;
            fv.z = fa.z + pa.z; fv.w = fa.w + pa.w;
        }
        short4v s4;
        s4[0] = f2bf(fv.x); s4[1] = f2bf(fv.y); s4[2] = f2bf(fv.z); s4[3] = f2bf(fv.w);
        *(short4v*)&fA[c][wq * 4] = s4;
        fBt[wq * 4 + 0][c] = s4[0];
        fBt[wq * 4 + 1][c] = s4[1];
        fBt[wq * 4 + 2][c] = s4[2];
        fBt[wq * 4 + 3][c] = s4[3];
    }
    __syncthreads();

    // ---------------- Phase B: q,k = [Wq;Wk] f + bias via MFMA ----------------
    f32x4 acc[4][3];
    #pragma unroll
    for (int mf = 0; mf < 4; ++mf)
        #pragma unroll
        for (int nf = 0; nf < 3; ++nf)
            acc[mf][nf] = (f32x4){0.f, 0.f, 0.f, 0.f};

    #pragma unroll
    for (int kk = 0; kk < 4; ++kk) {
        short8 bfr[3];
        #pragma unroll
        for (int nf = 0; nf < 3; ++nf)
            bfr[nf] = *(const short8*)&fBt[nf * 16 + lrow][kk * 32 + lgrp * 8];
        #pragma unroll
        for (int mf = 0; mf < 4; ++mf)
            #pragma unroll
            for (int nf = 0; nf < 3; ++nf)
                acc[mf][nf] = __builtin_amdgcn_mfma_f32_16x16x32_bf16(
                    afrag[mf][kk], bfr[nf], acc[mf][nf], 0, 0, 0);
    }

    // writeback transposed bf16: q -> qT (w rows 8..39), k -> kT (all, zero OOB)
    if (wid < 2) {
        #pragma unroll
        for (int mf = 0; mf < 4; ++mf)
            #pragma unroll
            for (int nf = 0; nf < 3; ++nf) {
                const int wl = nf * 16 + lrow;
                if (wl >= RR && wl < RR + TW) {
                    short4v s;
                    #pragma unroll
                    for (int reg = 0; reg < 4; ++reg)
                        s[reg] = f2bf(acc[mf][nf][reg] + bias_r[mf][reg]);
                    *(short4v*)&qT[wl - RR][mrow + mf * 16 + lgrp * 4] = s;
                }
            }
    } else {
        #pragma unroll
        for (int mf = 0; mf < 4; ++mf)
            #pragma unroll
            for (int nf = 0; nf < 3; ++nf) {
                const int wl = nf * 16 + lrow;
                const int w  = w0 + wl;
                const bool inb = (w >= 0 && w < WW);
                short4v s;
                #pragma unroll
                for (int reg = 0; reg < 4; ++reg)
                    s[reg] = inb ? f2bf(acc[mf][nf][reg] + bias_r[mf][reg]) : (short)0;
                *(short4v*)&kT[wl][mrow + mf * 16 + lgrp * 4] = s;
            }
    }
    __syncthreads();

    // ---------------- Phase C: S^T = (q^T k) / sqrt(C) via MFMA ---------------
    if (wid < 3) {
        const int nf = wid;          // wl' block 0..2
        f32x4 s0 = {0.f,0.f,0.f,0.f}, s1 = {0.f,0.f,0.f,0.f};
        #pragma unroll
        for (int kk = 0; kk < 4; ++kk) {
            const short8 a0 = *(const short8*)&qT[lrow     ][kk * 32 + lgrp * 8];
            const short8 a1 = *(const short8*)&qT[16 + lrow][kk * 32 + lgrp * 8];
            const short8 bb = *(const short8*)&kT[nf * 16 + lrow][kk * 32 + lgrp * 8];
            s0 = __builtin_amdgcn_mfma_f32_16x16x32_bf16(a0, bb, s0, 0, 0, 0);
            s1 = __builtin_amdgcn_mfma_f32_16x16x32_bf16(a1, bb, s1, 0, 0, 0);
        }
        const float isc = 0.08838834764831845f;   // 1/sqrt(128)
        *(f32x4*)&St[nf * 16 + lrow][lgrp * 4]      = s0 * isc;
        *(f32x4*)&St[nf * 16 + lrow][16 + lgrp * 4] = s1 * isc;
    }
    __syncthreads();

    // ---------------- softmax over 17 taps, build P (bf16) --------------------
    if (t < TW) {
        float sv[KWIN];
        float mx = -3.0e38f;
        #pragma unroll
        for (int j = 0; j < KWIN; ++j) { sv[j] = St[t + j][t]; mx = fmaxf(mx, sv[j]); }
        float sum = 0.f;
        #pragma unroll
        for (int j = 0; j < KWIN; ++j) { sv[j] = __expf(sv[j] - mx); sum += sv[j]; }
        const float inv = 1.f / sum;
        #pragma unroll
        for (int j = 0; j < KWIN; ++j) Pt[t][t + j] = f2bf(sv[j] * inv);
    }
    __syncthreads();

    // ---------------- Phase D: out = f . P^T via MFMA -------------------------
    {
        const int cb = wid * 32;
        f32x4 d00 = {0.f,0.f,0.f,0.f}, d01 = d00, d10 = d00, d11 = d00;
        #pragma unroll
        for (int kk = 0; kk < 2; ++kk) {
            const short8 a0 = *(const short8*)&fA[cb + lrow     ][kk * 32 + lgrp * 8];
            const short8 a1 = *(const short8*)&fA[cb + 16 + lrow][kk * 32 + lgrp * 8];
            const short8 b0 = *(const short8*)&Pt[lrow     ][kk * 32 + lgrp * 8];
            const short8 b1 = *(const short8*)&Pt[16 + lrow][kk * 32 + lgrp * 8];
            d00 = __builtin_amdgcn_mfma_f32_16x16x32_bf16(a0, b0, d00, 0, 0, 0);
            d01 = __builtin_amdgcn_mfma_f32_16x16x32_bf16(a0, b1, d01, 0, 0, 0);
            d10 = __builtin_amdgcn_mfma_f32_16x16x32_bf16(a1, b0, d10, 0, 0, 0);
            d11 = __builtin_amdgcn_mfma_f32_16x16x32_bf16(a1, b1, d11, 0, 0, 0);
        }
        const int wbase = wt * TW;
        #pragma unroll
        for (int reg = 0; reg < 4; ++reg) {
            const int c0 = cb + lgrp * 4 + reg;
            out[base + c0 * (HH * WW)        + wbase + lrow]      = d00[reg];
            out[base + c0 * (HH * WW)        + wbase + 16 + lrow] = d01[reg];
            out[base + (c0 + 16) * (HH * WW) + wbase + lrow]      = d10[reg];
            out[base + (c0 + 16) * (HH * WW) + wbase + 16 + lrow] = d11[reg];
        }
    }
}

extern "C" void kernel_launch(void* const* d_in, const int* in_sizes, int n_in,
                              void* d_out, int out_size, void* d_ws, size_t ws_size,
                              hipStream_t stream) {
    const float* feature  = (const float*)d_in[0];
    const float* position = (const float*)d_in[1];
    const float* Wq = (const float*)d_in[2];
    const float* bq = (const float*)d_in[3];
    const float* Wk = (const float*)d_in[4];
    const float* bk = (const float*)d_in[5];
    float* out = (float*)d_out;

    const dim3 grid(BB * HH * (WW / TW));   // 2048 blocks
    attn1d_fused<<<grid, NTHREADS, 0, stream>>>(feature, position, Wq, bq, Wk, bk, out);
}

// Round 5
// 49.105 us; speedup vs baseline: 3.2630x; 1.2687x over previous
//
#include <hip/hip_runtime.h>
#include <hip/hip_bf16.h>
#include <math.h>

#define BB 4
#define CCH 128     // channels
#define HH 64
#define WW 256
#define RR 8
#define KWIN 17
#define TW 32       // output w-tile per block
#define TWH 48      // TW + 2R (halo)
#define NTHREADS 256
#define PIT 136     // pitch (shorts) for [row][c] bf16 arrays (row stride 68 dw = 4 mod 32)
#define FAP 72      // fA pitch (shorts)
#define STP 36      // St pitch (floats)
#define PTP 72      // Pt pitch (shorts)

typedef __attribute__((ext_vector_type(8))) short short8;
typedef __attribute__((ext_vector_type(4))) short short4v;
typedef __attribute__((ext_vector_type(4))) float f32x4;

__device__ __forceinline__ short f2bf(float x) {
    union { __hip_bfloat16 b; short s; } u;
    u.b = __float2bfloat16(x);
    return u.s;
}

__global__ __launch_bounds__(NTHREADS, 3)
void attn1d_fused(const float* __restrict__ feature,
                  const float* __restrict__ position,
                  const float* __restrict__ Wq, const float* __restrict__ bq,
                  const float* __restrict__ Wk, const float* __restrict__ bk,
                  float* __restrict__ out)
{
    // Union region (13056 B): fBt lives Phase A->B; St (0..6911) lives C->softmax;
    // Pt (6912..11519) zeroed by wave 3 during C, written softmax, read D.
    __shared__ __align__(16) char uSm[TWH * PIT * 2];
    __shared__ __align__(16) short kT [TWH][PIT];   // 13056 B  k^T [wl][c]
    __shared__ __align__(16) short qT [TW ][PIT];   //  8704 B  q^T [w][c]
    __shared__ __align__(16) short fA [CCH][FAP];   // 18432 B  f [c][wl] (cols 48..63 zero)
                                                    // total 53248 B -> 3 blocks/CU
    short (*fBt)[PIT] = (short(*)[PIT])uSm;         // f^T [wl][c]
    float (*St)[STP]  = (float(*)[STP])uSm;         // S^T [wl'][w]
    short (*Pt)[PTP]  = (short(*)[PTP])(uSm + TWH * STP * 4);  // P [w][wl]

    const int t    = threadIdx.x;
    const int wid  = t >> 6;
    const int lane = t & 63;
    const int lrow = lane & 15;
    const int lgrp = lane >> 4;

    // XCD-chunked bijective swizzle (2048 % 8 == 0)
    int blk = blockIdx.x;
    blk = (blk & 7) * 256 + (blk >> 3);
    const int wt = blk & 7;
    const int bh = blk >> 3;
    const int h  = bh & (HH - 1);
    const int b  = bh >> 6;
    const int w0 = wt * TW - RR;
    const int base = ((b * CCH) * HH + h) * WW;

    // ---- A-fragments: rows of Wq (waves 0,1) / Wk (waves 2,3), bf16 in regs --
    const int   mrow = (wid & 1) * 64;
    const float* Wmat = (wid < 2) ? Wq : Wk;
    const float* bvec = (wid < 2) ? bq : bk;

    short8 afrag[4][4];   // [mf][kk]
    #pragma unroll
    for (int mf = 0; mf < 4; ++mf) {
        const float* wrow = Wmat + (mrow + mf * 16 + lrow) * CCH;
        #pragma unroll
        for (int kk = 0; kk < 4; ++kk) {
            const float* p = wrow + kk * 32 + lgrp * 8;
            const float4 a0 = *(const float4*)p;
            const float4 a1 = *(const float4*)(p + 4);
            short8 s;
            s[0] = f2bf(a0.x); s[1] = f2bf(a0.y); s[2] = f2bf(a0.z); s[3] = f2bf(a0.w);
            s[4] = f2bf(a1.x); s[5] = f2bf(a1.y); s[6] = f2bf(a1.z); s[7] = f2bf(a1.w);
            afrag[mf][kk] = s;
        }
    }
    float bias_r[4][4];
    #pragma unroll
    for (int mf = 0; mf < 4; ++mf)
        #pragma unroll
        for (int reg = 0; reg < 4; ++reg)
            bias_r[mf][reg] = bvec[mrow + mf * 16 + lgrp * 4 + reg];

    // ---------------- Phase A: stage f as fBt (transposed) + fA --------------
    #pragma unroll
    for (int i = 0; i < 6; ++i) {
        const int idx = i * NTHREADS + t;        // 1536 quads
        const int c  = idx / 12;
        const int wq = idx - c * 12;
        const int w  = w0 + wq * 4;              // quad fully in or out (w0 % 4 == 0)
        float4 fv = {0.f, 0.f, 0.f, 0.f};
        if (w >= 0 && w < WW) {
            const int off = base + c * (HH * WW) + w;
            const float4 fa = *(const float4*)(feature + off);
            const float4 pa = *(const float4*)(position + off);
            fv.x = fa.x + pa.x; fv.y = fa.y + pa.y;
            fv.z = fa.z + pa.z; fv.w = fa.w + pa.w;
        }
        short4v s4;
        s4[0] = f2bf(fv.x); s4[1] = f2bf(fv.y); s4[2] = f2bf(fv.z); s4[3] = f2bf(fv.w);
        *(short4v*)&fA[c][wq * 4] = s4;
        fBt[wq * 4 + 0][c] = s4[0];
        fBt[wq * 4 + 1][c] = s4[1];
        fBt[wq * 4 + 2][c] = s4[2];
        fBt[wq * 4 + 3][c] = s4[3];
    }
    {   // zero fA k-pad cols 48..63
        const short8 z = {0,0,0,0,0,0,0,0};
        const int zc = t >> 1, zs = t & 1;
        *(short8*)&fA[zc][48 + zs * 8] = z;
    }
    __syncthreads();

    // ---------------- Phase B: q,k = [Wq;Wk] f + bias via MFMA ----------------
    f32x4 acc[4][3];
    #pragma unroll
    for (int mf = 0; mf < 4; ++mf)
        #pragma unroll
        for (int nf = 0; nf < 3; ++nf)
            acc[mf][nf] = (f32x4){0.f, 0.f, 0.f, 0.f};

    #pragma unroll
    for (int kk = 0; kk < 4; ++kk) {
        short8 bfr[3];
        #pragma unroll
        for (int nf = 0; nf < 3; ++nf)
            bfr[nf] = *(const short8*)&fBt[nf * 16 + lrow][kk * 32 + lgrp * 8];
        #pragma unroll
        for (int mf = 0; mf < 4; ++mf)
            #pragma unroll
            for (int nf = 0; nf < 3; ++nf)
                acc[mf][nf] = __builtin_amdgcn_mfma_f32_16x16x32_bf16(
                    afrag[mf][kk], bfr[nf], acc[mf][nf], 0, 0, 0);
    }

    // writeback transposed bf16: q -> qT (w rows 8..39), k -> kT (all, zero OOB)
    if (wid < 2) {
        #pragma unroll
        for (int mf = 0; mf < 4; ++mf)
            #pragma unroll
            for (int nf = 0; nf < 3; ++nf) {
                const int wl = nf * 16 + lrow;
                if (wl >= RR && wl < RR + TW) {
                    short4v s;
                    #pragma unroll
                    for (int reg = 0; reg < 4; ++reg)
                        s[reg] = f2bf(acc[mf][nf][reg] + bias_r[mf][reg]);
                    *(short4v*)&qT[wl - RR][mrow + mf * 16 + lgrp * 4] = s;
                }
            }
    } else {
        #pragma unroll
        for (int mf = 0; mf < 4; ++mf)
            #pragma unroll
            for (int nf = 0; nf < 3; ++nf) {
                const int wl = nf * 16 + lrow;
                const int w  = w0 + wl;
                const bool inb = (w >= 0 && w < WW);
                short4v s;
                #pragma unroll
                for (int reg = 0; reg < 4; ++reg)
                    s[reg] = inb ? f2bf(acc[mf][nf][reg] + bias_r[mf][reg]) : (short)0;
                *(short4v*)&kT[wl][mrow + mf * 16 + lgrp * 4] = s;
            }
    }
    __syncthreads();   // fBt dead from here -> St/Pt may use its space

    // ---------------- Phase C: S^T = (q^T k) / sqrt(C) via MFMA ---------------
    if (wid < 3) {
        const int nf = wid;          // wl' block 0..2
        f32x4 s0 = {0.f,0.f,0.f,0.f}, s1 = {0.f,0.f,0.f,0.f};
        #pragma unroll
        for (int kk = 0; kk < 4; ++kk) {
            const short8 a0 = *(const short8*)&qT[lrow     ][kk * 32 + lgrp * 8];
            const short8 a1 = *(const short8*)&qT[16 + lrow][kk * 32 + lgrp * 8];
            const short8 bb = *(const short8*)&kT[nf * 16 + lrow][kk * 32 + lgrp * 8];
            s0 = __builtin_amdgcn_mfma_f32_16x16x32_bf16(a0, bb, s0, 0, 0, 0);
            s1 = __builtin_amdgcn_mfma_f32_16x16x32_bf16(a1, bb, s1, 0, 0, 0);
        }
        const float isc = 0.08838834764831845f;   // 1/sqrt(128)
        *(f32x4*)&St[nf * 16 + lrow][lgrp * 4]      = s0 * isc;
        *(f32x4*)&St[nf * 16 + lrow][16 + lgrp * 4] = s1 * isc;
    } else {
        // wave 3: zero-fill Pt (32 x 72 shorts = 288 short8 chunks)
        const short8 z = {0,0,0,0,0,0,0,0};
        short* p = &Pt[0][0];
        for (int i = lane; i < (TW * PTP) / 8; i += 64)
            *(short8*)(p + i * 8) = z;
    }
    __syncthreads();

    // ---------------- softmax over 17 taps (parallel: 4 threads/row) ---------
    if (t < TW * 4) {
        const int w = t >> 2, g = t & 3;
        const int nt = (g == 0) ? 5 : 4;          // taps j = g + 4i, plus j=16 for g==0
        float sv[5];
        float mx = -3.0e38f;
        #pragma unroll
        for (int i = 0; i < 5; ++i) {
            if (i < nt) {
                const int j = (i == 4) ? 16 : (g + i * 4);
                sv[i] = St[w + j][w];
                mx = fmaxf(mx, sv[i]);
            }
        }
        mx = fmaxf(mx, __shfl_xor(mx, 1, 4));
        mx = fmaxf(mx, __shfl_xor(mx, 2, 4));
        float sum = 0.f;
        #pragma unroll
        for (int i = 0; i < 5; ++i)
            if (i < nt) { sv[i] = __expf(sv[i] - mx); sum += sv[i]; }
        sum += __shfl_xor(sum, 1, 4);
        sum += __shfl_xor(sum, 2, 4);
        const float inv = 1.f / sum;
        #pragma unroll
        for (int i = 0; i < 5; ++i)
            if (i < nt) {
                const int j = (i == 4) ? 16 : (g + i * 4);
                Pt[w][w + j] = f2bf(sv[i] * inv);
            }
    }
    __syncthreads();

    // ---------------- Phase D: out = f . P^T via MFMA -------------------------
    {
        const int cb = wid * 32;
        f32x4 d00 = {0.f,0.f,0.f,0.f}, d01 = d00, d10 = d00, d11 = d00;
        #pragma unroll
        for (int kk = 0; kk < 2; ++kk) {
            const short8 a0 = *(const short8*)&fA[cb + lrow     ][kk * 32 + lgrp * 8];
            const short8 a1 = *(const short8*)&fA[cb + 16 + lrow][kk * 32 + lgrp * 8];
            const short8 b0 = *(const short8*)&Pt[lrow     ][kk * 32 + lgrp * 8];
            const short8 b1 = *(const short8*)&Pt[16 + lrow][kk * 32 + lgrp * 8];
            d00 = __builtin_amdgcn_mfma_f32_16x16x32_bf16(a0, b0, d00, 0, 0, 0);
            d01 = __builtin_amdgcn_mfma_f32_16x16x32_bf16(a0, b1, d01, 0, 0, 0);
            d10 = __builtin_amdgcn_mfma_f32_16x16x32_bf16(a1, b0, d10, 0, 0, 0);
            d11 = __builtin_amdgcn_mfma_f32_16x16x32_bf16(a1, b1, d11, 0, 0, 0);
        }
        const int wbase = wt * TW;
        #pragma unroll
        for (int reg = 0; reg < 4; ++reg) {
            const int c0 = cb + lgrp * 4 + reg;
            out[base + c0 * (HH * WW)        + wbase + lrow]      = d00[reg];
            out[base + c0 * (HH * WW)        + wbase + 16 + lrow] = d01[reg];
            out[base + (c0 + 16) * (HH * WW) + wbase + lrow]      = d10[reg];
            out[base + (c0 + 16) * (HH * WW) + wbase + 16 + lrow] = d11[reg];
        }
    }
}

extern "C" void kernel_launch(void* const* d_in, const int* in_sizes, int n_in,
                              void* d_out, int out_size, void* d_ws, size_t ws_size,
                              hipStream_t stream) {
    const float* feature  = (const float*)d_in[0];
    const float* position = (const float*)d_in[1];
    const float* Wq = (const float*)d_in[2];
    const float* bq = (const float*)d_in[3];
    const float* Wk = (const float*)d_in[4];
    const float* bk = (const float*)d_in[5];
    float* out = (float*)d_out;

    const dim3 grid(BB * HH * (WW / TW));   // 2048 blocks
    attn1d_fused<<<grid, NTHREADS, 0, stream>>>(feature, position, Wq, bq, Wk, bk, out);
}